// Round 1
// baseline (3945.362 us; speedup 1.0000x reference)
//
#include <hip/hip_runtime.h>

// EP model: all-GEMM formulation.
// Free phase is the exact fixed point -> g0 == 0 bitwise, ep_grads = gb/BETA.
// Iter 0 (coupled) with zero residuals: g3=beta*(s3-y), g2=g3@W2^T, g1=g2@W1^T.
// Iters 1..19 generic: r2=s2-s1@W1, r3=s3-s2@W2,
//   s1 = (1-lr)s1 + lr*c1 + lr*(r2@W1^T)
//   s2 = s2 - lr*r2 + lr*(r3@W2^T)
//   s3 = (1-lr*beta)s3 - lr*r3 + lr*beta*y
// Final: ep0 = -(1/beta) x^T(s1-c1); ep1 = -(1/beta) s1^T r2; ep2 = -(1/beta) s2^T r3
// loss = mean((c3-y)^2)

namespace {

constexpr int BATCH = 1024;
constexpr float LR   = 0.5f;
constexpr float BETA = 1e-3f;

constexpr int TILE = 64;
constexpr int KTS  = 32;

// MODE: 0 = NN (A MxK, B KxN), 1 = NT (A MxK, B NxK), 2 = TN (A KxM, B KxN)
// out[m,n] = alpha*acc + c0*E0[m,n] (if E0) + c1e*E1[m,n] (if E1)
template<int MODE>
__global__ __launch_bounds__(256) void gemm_k(
    const float* __restrict__ A, const float* __restrict__ Bm,
    float* __restrict__ out, const float* __restrict__ E0,
    const float* __restrict__ E1, float alpha, float c0, float c1e,
    int M, int N, int K)
{
  __shared__ __align__(16) float As[KTS][TILE + 4];
  __shared__ __align__(16) float Bs[KTS][TILE + 4];
  const int tid = threadIdx.x;
  const int m0 = blockIdx.y * TILE;
  const int n0 = blockIdx.x * TILE;
  const int tm = tid >> 4;   // 0..15
  const int tn = tid & 15;   // 0..15

  float acc[4][4] = {};

  for (int k0 = 0; k0 < K; k0 += KTS) {
    // ---- stage A tile into As[k][m] ----
    if (MODE == 0 || MODE == 1) {
      // A row-major MxK: rows contiguous along K -> transpose into LDS
      #pragma unroll
      for (int it = 0; it < 2; ++it) {
        const int i  = tid + it * 256;     // 0..511
        const int r  = i >> 3;             // tile row 0..63
        const int cq = i & 7;              // k-float4 0..7
        const float4 v = *(const float4*)(A + (size_t)(m0 + r) * K + k0 + cq * 4);
        As[cq*4+0][r] = v.x; As[cq*4+1][r] = v.y;
        As[cq*4+2][r] = v.z; As[cq*4+3][r] = v.w;
      }
    } else {
      // A row-major KxM: direct copy
      #pragma unroll
      for (int it = 0; it < 2; ++it) {
        const int i  = tid + it * 256;
        const int c  = i >> 4;             // 0..31
        const int jq = i & 15;             // 0..15
        *(float4*)&As[c][jq*4] =
            *(const float4*)(A + (size_t)(k0 + c) * M + m0 + jq * 4);
      }
    }
    // ---- stage B tile into Bs[k][n] ----
    if (MODE == 1) {
      // B row-major NxK -> transpose
      #pragma unroll
      for (int it = 0; it < 2; ++it) {
        const int i  = tid + it * 256;
        const int r  = i >> 3;
        const int cq = i & 7;
        const float4 v = *(const float4*)(Bm + (size_t)(n0 + r) * K + k0 + cq * 4);
        Bs[cq*4+0][r] = v.x; Bs[cq*4+1][r] = v.y;
        Bs[cq*4+2][r] = v.z; Bs[cq*4+3][r] = v.w;
      }
    } else {
      // B row-major KxN: direct
      #pragma unroll
      for (int it = 0; it < 2; ++it) {
        const int i  = tid + it * 256;
        const int c  = i >> 4;
        const int jq = i & 15;
        *(float4*)&Bs[c][jq*4] =
            *(const float4*)(Bm + (size_t)(k0 + c) * N + n0 + jq * 4);
      }
    }
    __syncthreads();

    #pragma unroll
    for (int k = 0; k < KTS; ++k) {
      const float4 av = *(const float4*)&As[k][tm * 4];
      const float4 bv = *(const float4*)&Bs[k][tn * 4];
      const float a_[4] = {av.x, av.y, av.z, av.w};
      const float b_[4] = {bv.x, bv.y, bv.z, bv.w};
      #pragma unroll
      for (int i = 0; i < 4; ++i)
        #pragma unroll
        for (int j = 0; j < 4; ++j)
          acc[i][j] = fmaf(a_[i], b_[j], acc[i][j]);
    }
    __syncthreads();
  }

  // ---- epilogue ----
  #pragma unroll
  for (int i = 0; i < 4; ++i) {
    const int m = m0 + tm * 4 + i;
    const size_t idx = (size_t)m * N + n0 + tn * 4;
    float4 v;
    v.x = alpha * acc[i][0]; v.y = alpha * acc[i][1];
    v.z = alpha * acc[i][2]; v.w = alpha * acc[i][3];
    if (E0) {
      const float4 e = *(const float4*)(E0 + idx);
      v.x = fmaf(c0, e.x, v.x); v.y = fmaf(c0, e.y, v.y);
      v.z = fmaf(c0, e.z, v.z); v.w = fmaf(c0, e.w, v.w);
    }
    if (E1) {
      const float4 e = *(const float4*)(E1 + idx);
      v.x = fmaf(c1e, e.x, v.x); v.y = fmaf(c1e, e.y, v.y);
      v.z = fmaf(c1e, e.z, v.z); v.w = fmaf(c1e, e.w, v.w);
    }
    *(float4*)(out + idx) = v;
  }
}

// r3 = beta*(s3 - y); s3 -= lr*r3
__global__ void ew_iter0_s3(float* __restrict__ s3, float* __restrict__ r3,
                            const float* __restrict__ y, int n) {
  int i = blockIdx.x * blockDim.x + threadIdx.x;
  if (i < n) {
    float r = BETA * (s3[i] - y[i]);
    r3[i] = r;
    s3[i] -= LR * r;
  }
}

// dst += a*src
__global__ void ew_axpy(float* __restrict__ dst, const float* __restrict__ src,
                        float a, int n) {
  int i = blockIdx.x * blockDim.x + threadIdx.x;
  if (i < n) dst[i] = fmaf(a, src[i], dst[i]);
}

// s3 = (1 - lr*beta)*s3 - lr*r3 + lr*beta*y
__global__ void ew_s3_update(float* __restrict__ s3, const float* __restrict__ r3,
                             const float* __restrict__ y, int n) {
  int i = blockIdx.x * blockDim.x + threadIdx.x;
  if (i < n) {
    float v = (1.0f - LR * BETA) * s3[i];
    v = fmaf(-LR, r3[i], v);
    v = fmaf(LR * BETA, y[i], v);
    s3[i] = v;
  }
}

// out = a - b
__global__ void ew_sub(float* __restrict__ out, const float* __restrict__ a,
                       const float* __restrict__ b, int n) {
  int i = blockIdx.x * blockDim.x + threadIdx.x;
  if (i < n) out[i] = a[i] - b[i];
}

__global__ void loss_partial(const float* __restrict__ c3,
                             const float* __restrict__ y,
                             float* __restrict__ partials, int n) {
  __shared__ float red[256];
  float s = 0.f;
  for (int i = blockIdx.x * 256 + threadIdx.x; i < n; i += gridDim.x * 256) {
    float d = c3[i] - y[i];
    s = fmaf(d, d, s);
  }
  red[threadIdx.x] = s;
  __syncthreads();
  for (int off = 128; off > 0; off >>= 1) {
    if (threadIdx.x < off) red[threadIdx.x] += red[threadIdx.x + off];
    __syncthreads();
  }
  if (threadIdx.x == 0) partials[blockIdx.x] = red[0];
}

__global__ void loss_final(const float* __restrict__ partials,
                           float* __restrict__ out, int np, float inv_n) {
  __shared__ float red[256];
  float s = 0.f;
  for (int i = threadIdx.x; i < np; i += 256) s += partials[i];
  red[threadIdx.x] = s;
  __syncthreads();
  for (int off = 128; off > 0; off >>= 1) {
    if (threadIdx.x < off) red[threadIdx.x] += red[threadIdx.x + off];
    __syncthreads();
  }
  if (threadIdx.x == 0) out[0] = red[0] * inv_n;
}

}  // namespace

extern "C" void kernel_launch(void* const* d_in, const int* in_sizes, int n_in,
                              void* d_out, int out_size, void* d_ws, size_t ws_size,
                              hipStream_t stream) {
  const float* x  = (const float*)d_in[0];  // 1024 x 1024
  const float* y  = (const float*)d_in[1];  // 1024 x 512
  const float* W0 = (const float*)d_in[2];  // 1024 x 1024
  const float* W1 = (const float*)d_in[3];  // 1024 x 1024
  const float* W2 = (const float*)d_in[4];  // 1024 x 512
  float* out = (float*)d_out;

  const int D1 = 1024, D3 = 512;
  const int N_BIG = BATCH * D1;   // 1,048,576
  const int N_SML = BATCH * D3;   // 524,288

  float* ws = (float*)d_ws;
  float* s1 = ws;                  // 1M
  float* s2 = s1 + N_BIG;          // 1M
  float* s3 = s2 + N_BIG;          // 512K
  float* c1 = s3 + N_SML;          // 1M
  float* c3 = c1 + N_BIG;          // 512K
  float* r2 = c3 + N_SML;          // 1M
  float* r3 = r2 + N_BIG;          // 512K
  float* r1 = r3 + N_SML;          // 1M
  float* partials = r1 + N_BIG;    // 512

  float* ep0 = out;
  float* ep1 = out + 1048576;
  float* ep2 = out + 2097152;
  float* lossp = out + 2621440;

  const dim3 blk(256);
  auto g2d = [](int M, int N) { return dim3(N / TILE, M / TILE); };
  const int EB = 256;
  const float inv_beta = -1.0f / BETA;  // -1000

  // ---- forward chain ----
  gemm_k<0><<<g2d(BATCH, 1024), blk, 0, stream>>>(x, W0, c1, nullptr, nullptr,
                                                  1.f, 0.f, 0.f, BATCH, 1024, 1024);
  gemm_k<0><<<g2d(BATCH, 1024), blk, 0, stream>>>(c1, W1, s2, nullptr, nullptr,
                                                  1.f, 0.f, 0.f, BATCH, 1024, 1024);
  gemm_k<0><<<g2d(BATCH, 512), blk, 0, stream>>>(s2, W2, c3, nullptr, nullptr,
                                                 1.f, 0.f, 0.f, BATCH, 512, 1024);
  hipMemcpyAsync(s1, c1, (size_t)N_BIG * 4, hipMemcpyDeviceToDevice, stream);
  hipMemcpyAsync(s3, c3, (size_t)N_SML * 4, hipMemcpyDeviceToDevice, stream);

  // ---- iteration 0 (coupled; residuals are exactly zero) ----
  ew_iter0_s3<<<(N_SML + EB - 1) / EB, EB, 0, stream>>>(s3, r3, y, N_SML);
  // g2 = r3 @ W2^T  -> store in r2
  gemm_k<1><<<g2d(BATCH, 1024), blk, 0, stream>>>(r3, W2, r2, nullptr, nullptr,
                                                  1.f, 0.f, 0.f, BATCH, 1024, 512);
  ew_axpy<<<(N_BIG + EB - 1) / EB, EB, 0, stream>>>(s2, r2, -LR, N_BIG);
  // s1 = s1 - lr*(r2 @ W1^T)
  gemm_k<1><<<g2d(BATCH, 1024), blk, 0, stream>>>(r2, W1, s1, s1, nullptr,
                                                  -LR, 1.f, 0.f, BATCH, 1024, 1024);

  // ---- iterations 1..19 ----
  for (int it = 1; it < 20; ++it) {
    // r2 = s2 - s1@W1
    gemm_k<0><<<g2d(BATCH, 1024), blk, 0, stream>>>(s1, W1, r2, s2, nullptr,
                                                    -1.f, 1.f, 0.f, BATCH, 1024, 1024);
    // r3 = s3 - s2@W2
    gemm_k<0><<<g2d(BATCH, 512), blk, 0, stream>>>(s2, W2, r3, s3, nullptr,
                                                   -1.f, 1.f, 0.f, BATCH, 512, 1024);
    // s3 update (elementwise)
    ew_s3_update<<<(N_SML + EB - 1) / EB, EB, 0, stream>>>(s3, r3, y, N_SML);
    // s1 = (1-lr)*s1 + lr*c1 + lr*(r2@W1^T)
    gemm_k<1><<<g2d(BATCH, 1024), blk, 0, stream>>>(r2, W1, s1, s1, c1,
                                                    LR, 1.f - LR, LR, BATCH, 1024, 1024);
    // s2 = s2 - lr*r2 + lr*(r3@W2^T)
    gemm_k<1><<<g2d(BATCH, 1024), blk, 0, stream>>>(r3, W2, s2, s2, r2,
                                                    LR, 1.f, -LR, BATCH, 1024, 512);
  }

  // ---- final residuals ----
  gemm_k<0><<<g2d(BATCH, 1024), blk, 0, stream>>>(s1, W1, r2, s2, nullptr,
                                                  -1.f, 1.f, 0.f, BATCH, 1024, 1024);
  gemm_k<0><<<g2d(BATCH, 512), blk, 0, stream>>>(s2, W2, r3, s3, nullptr,
                                                 -1.f, 1.f, 0.f, BATCH, 512, 1024);
  ew_sub<<<(N_BIG + EB - 1) / EB, EB, 0, stream>>>(r1, s1, c1, N_BIG);

  // ---- EP weight grads: ep_i = -(1/beta) * s_i^T @ r_{i+1} ----
  gemm_k<2><<<g2d(1024, 1024), blk, 0, stream>>>(x, r1, ep0, nullptr, nullptr,
                                                 inv_beta, 0.f, 0.f, 1024, 1024, BATCH);
  gemm_k<2><<<g2d(1024, 1024), blk, 0, stream>>>(s1, r2, ep1, nullptr, nullptr,
                                                 inv_beta, 0.f, 0.f, 1024, 1024, BATCH);
  gemm_k<2><<<g2d(1024, 512), blk, 0, stream>>>(s2, r3, ep2, nullptr, nullptr,
                                                inv_beta, 0.f, 0.f, 1024, 512, BATCH);

  // ---- loss = mean((c3 - y)^2) ----
  loss_partial<<<512, 256, 0, stream>>>(c3, y, partials, N_SML);
  loss_final<<<1, 256, 0, stream>>>(partials, lossp, 512, 1.0f / (float)N_SML);
}

// Round 2
// 1820.316 us; speedup vs baseline: 2.1674x; 2.1674x over previous
//
#include <hip/hip_runtime.h>

// EP model, all-GEMM formulation, split-bf16 MFMA implementation.
// Math identical to previous round (verified): free phase exact fixed point,
// iter0 degenerate, 19 generic relaxation iters, EP grads = gb/beta.
//
// Each fp32 GEMM is computed as 3 bf16 MFMA products: Ah*Bh + Ah*Bl + Al*Bh,
// where X = Xh + Xl, Xh = bf16(X), Xl = bf16(X - Xh). Abs error ~2e-6 per
// element of s@W, giving ~0.1 extra absmax after the /beta amplification.

typedef float f32x4 __attribute__((ext_vector_type(4)));
typedef __bf16 bf16x8 __attribute__((ext_vector_type(8)));
typedef unsigned short u16;
typedef unsigned int u32;

namespace {

constexpr float LR = 0.5f;
constexpr float BETA = 1e-3f;

__device__ inline void splitbf(float v, u16& h, u16& l) {
  __bf16 hb = (__bf16)v;
  float hf = (float)hb;
  __bf16 lb = (__bf16)(v - hf);
  h = __builtin_bit_cast(u16, hb);
  l = __builtin_bit_cast(u16, lb);
}

__device__ inline u32 pack2(u16 a, u16 b) { return (u32)a | ((u32)b << 16); }

// ---------------------------------------------------------------------------
// NT split-bf16 MFMA GEMM: C[m,n] = alpha * sum_k A[m,k]*B[n,k] (+ epilogue)
// A,B given as bf16 hi/lo pairs, row-major [rows][K].
// 64x64 tile, BK=32, 256 threads (4 waves, each 32x32 via 2x2 16x16x32 frags).
// ---------------------------------------------------------------------------
template <bool HASE0, bool HASE1, bool WSPLIT>
__global__ __launch_bounds__(256) void gemm_nt(
    const u16* __restrict__ Ah, const u16* __restrict__ Al,
    const u16* __restrict__ Bh, const u16* __restrict__ Bl,
    float* outf, u16* Oh, u16* Ol,
    const float* E0, const float* E1,
    float alpha, float c0, float c1e, int M, int N, int K) {
  __shared__ short lbuf[2][4][64 * 32];  // [dbuf][op Ah,Al,Bh,Bl][64 rows x 32 k]
  const int tid = threadIdx.x;
  const int lane = tid & 63;
  const int w = tid >> 6;
  const int wm = (w >> 1) << 5;
  const int wn = (w & 1) << 5;
  const int m0 = blockIdx.y << 6;
  const int n0 = blockIdx.x << 6;

  // staging: thread -> (row, 8-elem slot) of each operand tile
  const int srow = tid >> 2;   // 0..63
  const int sslot = tid & 3;   // 0..3
  const u16* Ahp = Ah + (size_t)(m0 + srow) * K + sslot * 8;
  const u16* Alp = Al + (size_t)(m0 + srow) * K + sslot * 8;
  const u16* Bhp = Bh + (size_t)(n0 + srow) * K + sslot * 8;
  const u16* Blp = Bl + (size_t)(n0 + srow) * K + sslot * 8;
  // swizzled LDS byte offset (slot XOR keyed on (row>>1)&3 -> 2-way banks)
  const int wb = srow * 64 + ((sslot ^ ((srow >> 1) & 3)) << 4);

  // fragment read byte offsets (same swizzle)
  const int fs = lane >> 4;   // k-slot 0..3
  const int fr = lane & 15;
  int aoffb[2], boffb[2];
#pragma unroll
  for (int i = 0; i < 2; ++i) {
    const int m = wm + 16 * i + fr;
    aoffb[i] = m * 64 + ((fs ^ ((m >> 1) & 3)) << 4);
    const int n = wn + 16 * i + fr;
    boffb[i] = n * 64 + ((fs ^ ((n >> 1) & 3)) << 4);
  }

  f32x4 acc[2][2] = {};
  const int nk = K >> 5;

  uint4 vAh = *(const uint4*)(Ahp);
  uint4 vAl = *(const uint4*)(Alp);
  uint4 vBh = *(const uint4*)(Bhp);
  uint4 vBl = *(const uint4*)(Blp);
  {
    char* b0 = (char*)&lbuf[0][0][0];
    *(uint4*)(b0 + 0 * 4096 + wb) = vAh;
    *(uint4*)(b0 + 1 * 4096 + wb) = vAl;
    *(uint4*)(b0 + 2 * 4096 + wb) = vBh;
    *(uint4*)(b0 + 3 * 4096 + wb) = vBl;
  }
  __syncthreads();

  int cur = 0;
  for (int s = 0; s < nk; ++s) {
    if (s + 1 < nk) {  // issue next k-block loads early (hide under MFMA)
      const int ke = (s + 1) << 5;
      vAh = *(const uint4*)(Ahp + ke);
      vAl = *(const uint4*)(Alp + ke);
      vBh = *(const uint4*)(Bhp + ke);
      vBl = *(const uint4*)(Blp + ke);
    }
    const char* base = (const char*)&lbuf[cur][0][0];
    bf16x8 ah[2], al[2], bh[2], bl[2];
#pragma unroll
    for (int i = 0; i < 2; ++i) {
      ah[i] = *(const bf16x8*)(base + aoffb[i]);
      al[i] = *(const bf16x8*)(base + 4096 + aoffb[i]);
      bh[i] = *(const bf16x8*)(base + 8192 + boffb[i]);
      bl[i] = *(const bf16x8*)(base + 12288 + boffb[i]);
    }
#pragma unroll
    for (int i = 0; i < 2; ++i)
#pragma unroll
      for (int j = 0; j < 2; ++j) {
        acc[i][j] = __builtin_amdgcn_mfma_f32_16x16x32_bf16(ah[i], bh[j], acc[i][j], 0, 0, 0);
        acc[i][j] = __builtin_amdgcn_mfma_f32_16x16x32_bf16(ah[i], bl[j], acc[i][j], 0, 0, 0);
        acc[i][j] = __builtin_amdgcn_mfma_f32_16x16x32_bf16(al[i], bh[j], acc[i][j], 0, 0, 0);
      }
    if (s + 1 < nk) {  // commit next block into the other buffer
      char* bo = (char*)&lbuf[cur ^ 1][0][0];
      *(uint4*)(bo + 0 * 4096 + wb) = vAh;
      *(uint4*)(bo + 1 * 4096 + wb) = vAl;
      *(uint4*)(bo + 2 * 4096 + wb) = vBh;
      *(uint4*)(bo + 3 * 4096 + wb) = vBl;
    }
    __syncthreads();
    cur ^= 1;
  }

  // epilogue: C/D layout col=lane&15, row=(lane>>4)*4+reg (HW-verified)
#pragma unroll
  for (int i = 0; i < 2; ++i)
#pragma unroll
    for (int j = 0; j < 2; ++j)
#pragma unroll
      for (int r = 0; r < 4; ++r) {
        const int gm = m0 + wm + 16 * i + ((lane >> 4) << 2) + r;
        const int gn = n0 + wn + 16 * j + (lane & 15);
        const size_t idx = (size_t)gm * N + gn;
        float v = alpha * acc[i][j][r];
        if (HASE0) v = fmaf(c0, E0[idx], v);
        if (HASE1) v = fmaf(c1e, E1[idx], v);
        outf[idx] = v;
        if (WSPLIT) {
          u16 h, l;
          splitbf(v, h, l);
          Oh[idx] = h;
          Ol[idx] = l;
        }
      }
}

// ---------------------------------------------------------------------------
// straight split: fp32 row-major -> bf16 hi/lo row-major (8 elems/thread)
// ---------------------------------------------------------------------------
__global__ void split_s(const float* __restrict__ src, u16* __restrict__ oh,
                        u16* __restrict__ ol, int ngrp) {
  const int g = blockIdx.x * blockDim.x + threadIdx.x;
  if (g >= ngrp) return;
  const int i = g * 8;
  const float4 a = *(const float4*)(src + i);
  const float4 b = *(const float4*)(src + i + 4);
  const float v[8] = {a.x, a.y, a.z, a.w, b.x, b.y, b.z, b.w};
  u16 h[8], l[8];
#pragma unroll
  for (int j = 0; j < 8; ++j) splitbf(v[j], h[j], l[j]);
  *(uint4*)(oh + i) = make_uint4(pack2(h[0], h[1]), pack2(h[2], h[3]),
                                 pack2(h[4], h[5]), pack2(h[6], h[7]));
  *(uint4*)(ol + i) = make_uint4(pack2(l[0], l[1]), pack2(l[2], l[3]),
                                 pack2(l[4], l[5]), pack2(l[6], l[7]));
}

// ---------------------------------------------------------------------------
// transpose split: out[c][r] = split(a[r][c] (- b[r][c])), in R x C row-major
// grid (C/64, R/64)
// ---------------------------------------------------------------------------
template <bool SUB>
__global__ __launch_bounds__(256) void split_t(const float* __restrict__ a,
                                               const float* __restrict__ b,
                                               u16* __restrict__ oh,
                                               u16* __restrict__ ol, int R, int C) {
  __shared__ float tile[64][65];
  const int tid = threadIdx.x;
  const int c0 = blockIdx.x << 6, r0 = blockIdx.y << 6;
#pragma unroll
  for (int q = 0; q < 16; ++q) {
    const int i = q * 256 + tid;
    const int r = i >> 6, c = i & 63;
    const size_t src = (size_t)(r0 + r) * C + c0 + c;
    float v = a[src];
    if (SUB) v -= b[src];
    tile[r][c] = v;
  }
  __syncthreads();
#pragma unroll
  for (int q = 0; q < 2; ++q) {
    const int g = q * 256 + tid;
    const int oc = g >> 3, os = g & 7;
    u16 h[8], l[8];
#pragma unroll
    for (int j = 0; j < 8; ++j) splitbf(tile[os * 8 + j][oc], h[j], l[j]);
    const size_t dst = (size_t)(c0 + oc) * R + r0 + os * 8;
    *(uint4*)(oh + dst) = make_uint4(pack2(h[0], h[1]), pack2(h[2], h[3]),
                                     pack2(h[4], h[5]), pack2(h[6], h[7]));
    *(uint4*)(ol + dst) = make_uint4(pack2(l[0], l[1]), pack2(l[2], l[3]),
                                     pack2(l[4], l[5]), pack2(l[6], l[7]));
  }
}

// ---------------------------------------------------------------------------
// elementwise kernels (8 elems/thread)
// ---------------------------------------------------------------------------
// r3 = beta*(s3-y) [fp32 + split]; s3 -= lr*r3
__global__ void ew_iter0(float* s3, float* r3f, u16* r3h, u16* r3l,
                         const float* __restrict__ y, int ngrp) {
  const int g = blockIdx.x * blockDim.x + threadIdx.x;
  if (g >= ngrp) return;
  const int i = g * 8;
  const float4 s0 = *(const float4*)(s3 + i);
  const float4 s1v = *(const float4*)(s3 + i + 4);
  const float4 y0 = *(const float4*)(y + i);
  const float4 y1 = *(const float4*)(y + i + 4);
  float sv[8] = {s0.x, s0.y, s0.z, s0.w, s1v.x, s1v.y, s1v.z, s1v.w};
  const float yv[8] = {y0.x, y0.y, y0.z, y0.w, y1.x, y1.y, y1.z, y1.w};
  float rv[8];
  u16 h[8], l[8];
#pragma unroll
  for (int j = 0; j < 8; ++j) {
    rv[j] = BETA * (sv[j] - yv[j]);
    splitbf(rv[j], h[j], l[j]);
    sv[j] = fmaf(-LR, rv[j], sv[j]);
  }
  *(float4*)(r3f + i) = make_float4(rv[0], rv[1], rv[2], rv[3]);
  *(float4*)(r3f + i + 4) = make_float4(rv[4], rv[5], rv[6], rv[7]);
  *(uint4*)(r3h + i) = make_uint4(pack2(h[0], h[1]), pack2(h[2], h[3]),
                                  pack2(h[4], h[5]), pack2(h[6], h[7]));
  *(uint4*)(r3l + i) = make_uint4(pack2(l[0], l[1]), pack2(l[2], l[3]),
                                  pack2(l[4], l[5]), pack2(l[6], l[7]));
  *(float4*)(s3 + i) = make_float4(sv[0], sv[1], sv[2], sv[3]);
  *(float4*)(s3 + i + 4) = make_float4(sv[4], sv[5], sv[6], sv[7]);
}

// s2 = s2 - lr*r2 [fp32 + split]
__global__ void ew_axpy_s2(float* s2, u16* s2h, u16* s2l,
                           const float* __restrict__ r2, int ngrp) {
  const int g = blockIdx.x * blockDim.x + threadIdx.x;
  if (g >= ngrp) return;
  const int i = g * 8;
  const float4 a0 = *(const float4*)(s2 + i);
  const float4 a1 = *(const float4*)(s2 + i + 4);
  const float4 b0 = *(const float4*)(r2 + i);
  const float4 b1 = *(const float4*)(r2 + i + 4);
  float sv[8] = {a0.x, a0.y, a0.z, a0.w, a1.x, a1.y, a1.z, a1.w};
  const float rv[8] = {b0.x, b0.y, b0.z, b0.w, b1.x, b1.y, b1.z, b1.w};
  u16 h[8], l[8];
#pragma unroll
  for (int j = 0; j < 8; ++j) {
    sv[j] = fmaf(-LR, rv[j], sv[j]);
    splitbf(sv[j], h[j], l[j]);
  }
  *(float4*)(s2 + i) = make_float4(sv[0], sv[1], sv[2], sv[3]);
  *(float4*)(s2 + i + 4) = make_float4(sv[4], sv[5], sv[6], sv[7]);
  *(uint4*)(s2h + i) = make_uint4(pack2(h[0], h[1]), pack2(h[2], h[3]),
                                  pack2(h[4], h[5]), pack2(h[6], h[7]));
  *(uint4*)(s2l + i) = make_uint4(pack2(l[0], l[1]), pack2(l[2], l[3]),
                                  pack2(l[4], l[5]), pack2(l[6], l[7]));
}

// s3 = s3 - lr*r3 - lr*beta*(s3-y)
__global__ void ew_s3upd(float* s3, const float* __restrict__ r3,
                         const float* __restrict__ y, int ngrp) {
  const int g = blockIdx.x * blockDim.x + threadIdx.x;
  if (g >= ngrp) return;
  const int i = g * 8;
  const float4 a0 = *(const float4*)(s3 + i);
  const float4 a1 = *(const float4*)(s3 + i + 4);
  const float4 b0 = *(const float4*)(r3 + i);
  const float4 b1 = *(const float4*)(r3 + i + 4);
  const float4 y0 = *(const float4*)(y + i);
  const float4 y1 = *(const float4*)(y + i + 4);
  float sv[8] = {a0.x, a0.y, a0.z, a0.w, a1.x, a1.y, a1.z, a1.w};
  const float rv[8] = {b0.x, b0.y, b0.z, b0.w, b1.x, b1.y, b1.z, b1.w};
  const float yv[8] = {y0.x, y0.y, y0.z, y0.w, y1.x, y1.y, y1.z, y1.w};
#pragma unroll
  for (int j = 0; j < 8; ++j)
    sv[j] = sv[j] - LR * (rv[j] + BETA * (sv[j] - yv[j]));
  *(float4*)(s3 + i) = make_float4(sv[0], sv[1], sv[2], sv[3]);
  *(float4*)(s3 + i + 4) = make_float4(sv[4], sv[5], sv[6], sv[7]);
}

__global__ void loss_partial(const float* __restrict__ c3,
                             const float* __restrict__ y,
                             float* __restrict__ partials, int n) {
  __shared__ float red[256];
  float s = 0.f;
  for (int i = blockIdx.x * 256 + threadIdx.x; i < n; i += gridDim.x * 256) {
    const float d = c3[i] - y[i];
    s = fmaf(d, d, s);
  }
  red[threadIdx.x] = s;
  __syncthreads();
  for (int off = 128; off > 0; off >>= 1) {
    if (threadIdx.x < off) red[threadIdx.x] += red[threadIdx.x + off];
    __syncthreads();
  }
  if (threadIdx.x == 0) partials[blockIdx.x] = red[0];
}

__global__ void loss_final(const float* __restrict__ partials,
                           float* __restrict__ o, int np, float inv_n) {
  __shared__ float red[256];
  float s = 0.f;
  for (int i = threadIdx.x; i < np; i += 256) s += partials[i];
  red[threadIdx.x] = s;
  __syncthreads();
  for (int off = 128; off > 0; off >>= 1) {
    if (threadIdx.x < off) red[threadIdx.x] += red[threadIdx.x + off];
    __syncthreads();
  }
  if (threadIdx.x == 0) o[0] = red[0] * inv_n;
}

}  // namespace

extern "C" void kernel_launch(void* const* d_in, const int* in_sizes, int n_in,
                              void* d_out, int out_size, void* d_ws, size_t ws_size,
                              hipStream_t stream) {
  const float* x  = (const float*)d_in[0];   // 1024 x 1024
  const float* y  = (const float*)d_in[1];   // 1024 x 512
  const float* W0 = (const float*)d_in[2];   // 1024 x 1024
  const float* W1 = (const float*)d_in[3];   // 1024 x 1024
  const float* W2 = (const float*)d_in[4];   // 1024 x 512
  float* out = (float*)d_out;

  const size_t M1 = 1u << 20;   // 1024*1024
  const size_t M5 = 1u << 19;   // 1024*512

  char* wp = (char*)d_ws;
  auto allocf = [&](size_t n) { float* p = (float*)wp; wp += n * 4; return p; };
  auto allocu = [&](size_t n) { u16* p = (u16*)wp; wp += n * 2; return p; };

  float* s1 = allocf(M1);
  float* s2 = allocf(M1);
  float* s3 = allocf(M5);
  float* c1 = allocf(M1);
  float* c3 = allocf(M5);
  float* r2 = allocf(M1);
  float* r3 = allocf(M5);
  float* partials = allocf(1024);

  u16* xh = allocu(M1);   u16* xl = allocu(M1);
  u16* c1h = allocu(M1);  u16* c1l = allocu(M1);
  u16* s1h = allocu(M1);  u16* s1l = allocu(M1);
  u16* s2h = allocu(M1);  u16* s2l = allocu(M1);
  u16* r2h = allocu(M1);  u16* r2l = allocu(M1);
  u16* r3h = allocu(M5);  u16* r3l = allocu(M5);
  u16* W0th = allocu(M1); u16* W0tl = allocu(M1);
  u16* W1h = allocu(M1);  u16* W1l = allocu(M1);
  u16* W1th = allocu(M1); u16* W1tl = allocu(M1);
  u16* W2h = allocu(M5);  u16* W2l = allocu(M5);
  u16* W2th = allocu(M5); u16* W2tl = allocu(M5);
  u16* xth = allocu(M1);  u16* xtl = allocu(M1);
  u16* s1th = allocu(M1); u16* s1tl = allocu(M1);
  u16* s2th = allocu(M1); u16* s2tl = allocu(M1);
  u16* r1th = allocu(M1); u16* r1tl = allocu(M1);
  u16* r2th = allocu(M1); u16* r2tl = allocu(M1);
  u16* r3th = allocu(M5); u16* r3tl = allocu(M5);

  float* ep0 = out;
  float* ep1 = out + M1;
  float* ep2 = out + 2 * M1;
  float* lossp = out + 2 * M1 + M5;

  const dim3 blk(256);
  const dim3 gFull(16, 16);  // N=1024, M=1024
  const dim3 gHalf(8, 16);   // N=512,  M=1024
  const int GB = 512, GS = 256;  // split/EW grids: 1M/8/256, 512K/8/256

  // ---- one-time splits of weights and x ----
  split_s<<<GB, blk, 0, stream>>>(W1, W1h, W1l, (int)(M1 / 8));
  split_s<<<GS, blk, 0, stream>>>(W2, W2h, W2l, (int)(M5 / 8));
  split_s<<<GB, blk, 0, stream>>>(x, xh, xl, (int)(M1 / 8));
  split_t<false><<<gFull, blk, 0, stream>>>(W0, nullptr, W0th, W0tl, 1024, 1024);
  split_t<false><<<gFull, blk, 0, stream>>>(W1, nullptr, W1th, W1tl, 1024, 1024);
  split_t<false><<<gHalf, blk, 0, stream>>>(W2, nullptr, W2th, W2tl, 1024, 512);

  // ---- forward chain ----
  gemm_nt<false, false, true><<<gFull, blk, 0, stream>>>(
      xh, xl, W0th, W0tl, c1, c1h, c1l, nullptr, nullptr, 1.f, 0.f, 0.f, 1024, 1024, 1024);
  gemm_nt<false, false, true><<<gFull, blk, 0, stream>>>(
      c1h, c1l, W1th, W1tl, s2, s2h, s2l, nullptr, nullptr, 1.f, 0.f, 0.f, 1024, 1024, 1024);
  gemm_nt<false, false, false><<<gHalf, blk, 0, stream>>>(
      s2h, s2l, W2th, W2tl, c3, nullptr, nullptr, nullptr, nullptr, 1.f, 0.f, 0.f, 1024, 512, 1024);
  hipMemcpyAsync(s1, c1, M1 * 4, hipMemcpyDeviceToDevice, stream);
  hipMemcpyAsync(s3, c3, M5 * 4, hipMemcpyDeviceToDevice, stream);

  // ---- iteration 0 (coupled; residuals exactly zero) ----
  ew_iter0<<<GS, blk, 0, stream>>>(s3, r3, r3h, r3l, y, (int)(M5 / 8));
  // r2(=g2) = r3 @ W2^T
  gemm_nt<false, false, true><<<gFull, blk, 0, stream>>>(
      r3h, r3l, W2h, W2l, r2, r2h, r2l, nullptr, nullptr, 1.f, 0.f, 0.f, 1024, 1024, 512);
  ew_axpy_s2<<<GB, blk, 0, stream>>>(s2, s2h, s2l, r2, (int)(M1 / 8));
  // s1 = s1 - lr*(r2 @ W1^T)
  gemm_nt<true, false, true><<<gFull, blk, 0, stream>>>(
      r2h, r2l, W1h, W1l, s1, s1h, s1l, s1, nullptr, -LR, 1.f, 0.f, 1024, 1024, 1024);

  // ---- iterations 1..19 ----
  for (int it = 1; it < 20; ++it) {
    // r2 = s2 - s1@W1
    gemm_nt<true, false, true><<<gFull, blk, 0, stream>>>(
        s1h, s1l, W1th, W1tl, r2, r2h, r2l, s2, nullptr, -1.f, 1.f, 0.f, 1024, 1024, 1024);
    // r3 = s3 - s2@W2
    gemm_nt<true, false, true><<<gHalf, blk, 0, stream>>>(
        s2h, s2l, W2th, W2tl, r3, r3h, r3l, s3, nullptr, -1.f, 1.f, 0.f, 1024, 512, 1024);
    ew_s3upd<<<GS, blk, 0, stream>>>(s3, r3, y, (int)(M5 / 8));
    // s1 = (1-lr)s1 + lr*c1 + lr*(r2@W1^T)
    gemm_nt<true, true, true><<<gFull, blk, 0, stream>>>(
        r2h, r2l, W1h, W1l, s1, s1h, s1l, s1, c1, LR, 1.f - LR, LR, 1024, 1024, 1024);
    // s2 = s2 - lr*r2 + lr*(r3@W2^T)
    gemm_nt<true, true, true><<<gFull, blk, 0, stream>>>(
        r3h, r3l, W2h, W2l, s2, s2h, s2l, s2, r2, LR, 1.f, -LR, 1024, 1024, 512);
  }

  // ---- final residuals (fp32 only) ----
  gemm_nt<true, false, false><<<gFull, blk, 0, stream>>>(
      s1h, s1l, W1th, W1tl, r2, nullptr, nullptr, s2, nullptr, -1.f, 1.f, 0.f, 1024, 1024, 1024);
  gemm_nt<true, false, false><<<gHalf, blk, 0, stream>>>(
      s2h, s2l, W2th, W2tl, r3, nullptr, nullptr, s3, nullptr, -1.f, 1.f, 0.f, 1024, 512, 1024);

  // ---- transposed splits for EP (TN) GEMMs ----
  split_t<false><<<gFull, blk, 0, stream>>>(x, nullptr, xth, xtl, 1024, 1024);
  split_t<false><<<gFull, blk, 0, stream>>>(s1, nullptr, s1th, s1tl, 1024, 1024);
  split_t<false><<<gFull, blk, 0, stream>>>(s2, nullptr, s2th, s2tl, 1024, 1024);
  split_t<true><<<gFull, blk, 0, stream>>>(s1, c1, r1th, r1tl, 1024, 1024);
  split_t<false><<<gFull, blk, 0, stream>>>(r2, nullptr, r2th, r2tl, 1024, 1024);
  split_t<false><<<gHalf, blk, 0, stream>>>(r3, nullptr, r3th, r3tl, 1024, 512);

  // ---- EP weight grads: ep_i = -(1/beta) * s_i^T @ r_{i+1} ----
  const float ib = -1.0f / BETA;
  gemm_nt<false, false, false><<<gFull, blk, 0, stream>>>(
      xth, xtl, r1th, r1tl, ep0, nullptr, nullptr, nullptr, nullptr, ib, 0.f, 0.f, 1024, 1024, 1024);
  gemm_nt<false, false, false><<<gFull, blk, 0, stream>>>(
      s1th, s1tl, r2th, r2tl, ep1, nullptr, nullptr, nullptr, nullptr, ib, 0.f, 0.f, 1024, 1024, 1024);
  gemm_nt<false, false, false><<<gHalf, blk, 0, stream>>>(
      s2th, s2tl, r3th, r3tl, ep2, nullptr, nullptr, nullptr, nullptr, ib, 0.f, 0.f, 1024, 512, 1024);

  // ---- loss = mean((c3 - y)^2) ----
  loss_partial<<<512, blk, 0, stream>>>(c3, y, partials, (int)M5);
  loss_final<<<1, blk, 0, stream>>>(partials, lossp, 512, 1.0f / (float)M5);
}